// Round 6
// baseline (205.952 us; speedup 1.0000x reference)
//
#include <hip/hip_runtime.h>

#define SCALE_F 173.71779276130078f   // 400 / ln(10)
#define BLOCK 256
#define TPT 4                         // consecutive tokens per thread

__global__ void zero_ws_kernel(float* __restrict__ ws, int n) {
    int i = blockIdx.x * 256 + threadIdx.x;
    if (i < n) ws[i] = 0.0f;          // zeroes num, den, and ticket (bits 0)
}

__global__ __launch_bounds__(BLOCK, 8) void strength_main_kernel(
    const float* __restrict__ x,    // [N][6]
    const float* __restrict__ W1,   // [6][32]
    const float* __restrict__ b1,   // [32]
    const float* __restrict__ wr,   // [32]
    const float* __restrict__ brp,  // scalar
    const float* __restrict__ wz,   // [32]
    const float* __restrict__ bzp,  // scalar
    const int*   __restrict__ seg,  // [N] sorted
    int N, int G, int nblocks,
    float* __restrict__ num,        // [G]
    float* __restrict__ den,        // [G]
    int*   __restrict__ ticket,     // [1]
    float* __restrict__ out)        // [G]
{
    const int tid  = threadIdx.x;
    const int lane = tid & 63;

    const int t0   = blockIdx.x * (BLOCK * TPT) + tid * TPT;
    const int kmax = (t0 >= N) ? 0 : ((N - t0 < TPT) ? (N - t0) : TPT);

    // ---- load 4 consecutive tokens (6 float4 = 96B) + 4 seg ids ----
    float a[TPT * 6];
    int   sg[TPT];
    if (kmax == TPT) {
        const float4* xp = (const float4*)(x + (size_t)t0 * 6);
        #pragma unroll
        for (int i = 0; i < 6; ++i) {
            float4 v = xp[i];
            a[4 * i + 0] = v.x; a[4 * i + 1] = v.y;
            a[4 * i + 2] = v.z; a[4 * i + 3] = v.w;
        }
        int4 s0v = *(const int4*)(seg + t0);
        sg[0] = s0v.x; sg[1] = s0v.y; sg[2] = s0v.z; sg[3] = s0v.w;
    } else {
        #pragma unroll
        for (int k = 0; k < TPT; ++k) {
            if (k < kmax) {
                const float* xp = x + (size_t)(t0 + k) * 6;
                #pragma unroll
                for (int i = 0; i < 6; ++i) a[k * 6 + i] = xp[i];
                sg[k] = seg[t0 + k];
            } else {
                #pragma unroll
                for (int i = 0; i < 6; ++i) a[k * 6 + i] = 0.0f;
                sg[k] = -1;
            }
        }
    }

    const float brv = *brp;   // uniform -> s_load
    const float bzv = *bzp;

    float r[TPT], z[TPT];
    #pragma unroll
    for (int k = 0; k < TPT; ++k) { r[k] = brv; z[k] = bzv; }

    // ---- MLP over 16 column-pairs. Weights are wave-uniform global derefs
    //      -> s_load into SGPRs; v_fma takes one SGPR operand for free.
    //      No LDS anywhere in this kernel. ----
    #pragma unroll 2
    for (int c = 0; c < 16; ++c) {
        const float2 w0 = *(const float2*)&W1[0 * 32 + 2 * c];
        const float2 w1 = *(const float2*)&W1[1 * 32 + 2 * c];
        const float2 w2 = *(const float2*)&W1[2 * 32 + 2 * c];
        const float2 w3 = *(const float2*)&W1[3 * 32 + 2 * c];
        const float2 w4 = *(const float2*)&W1[4 * 32 + 2 * c];
        const float2 w5 = *(const float2*)&W1[5 * 32 + 2 * c];
        const float2 bb = *(const float2*)&b1[2 * c];
        const float2 rr = *(const float2*)&wr[2 * c];
        const float2 zz = *(const float2*)&wz[2 * c];
        #pragma unroll
        for (int k = 0; k < TPT; ++k) {
            const float a0 = a[k*6+0], a1 = a[k*6+1], a2 = a[k*6+2];
            const float a3 = a[k*6+3], a4 = a[k*6+4], a5 = a[k*6+5];
            float h0 = fmaf(a0, w0.x, fmaf(a1, w1.x, fmaf(a2, w2.x,
                       fmaf(a3, w3.x, fmaf(a4, w4.x, fmaf(a5, w5.x, bb.x))))));
            float h1 = fmaf(a0, w0.y, fmaf(a1, w1.y, fmaf(a2, w2.y,
                       fmaf(a3, w3.y, fmaf(a4, w4.y, fmaf(a5, w5.y, bb.y))))));
            h0 = fmaxf(h0, 0.0f);
            h1 = fmaxf(h1, 0.0f);
            r[k] = fmaf(h0, rr.x, fmaf(h1, rr.y, r[k]));
            z[k] = fmaf(h0, zz.x, fmaf(h1, zz.y, z[k]));
        }
    }

    // ---- per-thread serial run accumulation; interior boundaries flush
    //      straight to global (adds commute -> correct) ----
    int   key = (kmax > 0) ? sg[0] : -1;
    float E = 0.0f, ER = 0.0f;
    #pragma unroll
    for (int k = 0; k < TPT; ++k) {
        if (k < kmax) {
            float e = __expf(z[k]);        // no max-shift: ratio invariant
            if (sg[k] != key) {            // rare (~1.5% of threads)
                atomicAdd(&den[key], E);
                atomicAdd(&num[key], ER);
                key = sg[k]; E = 0.0f; ER = 0.0f;
            }
            E += e; ER = fmaf(e, r[k], ER);
        }
    }

    // ---- one segmented inclusive scan per wave over lane tails ----
    #pragma unroll
    for (int d = 1; d < 64; d <<= 1) {
        int   k2 = __shfl_up(key, d);
        float E2 = __shfl_up(E,   d);
        float R2 = __shfl_up(ER,  d);
        if (lane >= d && k2 == key) { E += E2; ER += R2; }
    }
    int knext = __shfl_down(key, 1);
    bool last = (lane == 63) || (knext != key);
    if (last && key >= 0) {
        atomicAdd(&den[key], E);
        atomicAdd(&num[key], ER);
    }

    // ---- last-block-done finalize (fused; saves one kernel launch) ----
    __shared__ int isLast;
    __threadfence();                      // release my atomics before ticket
    if (tid == 0) {
        int t = __hip_atomic_fetch_add(ticket, 1, __ATOMIC_ACQ_REL,
                                       __HIP_MEMORY_SCOPE_AGENT);
        isLast = (t == nblocks - 1) ? 1 : 0;
    }
    __syncthreads();
    if (isLast) {
        __threadfence();                  // acquire all blocks' atomics
        for (int g = tid; g < G; g += BLOCK) {
            float d  = __hip_atomic_load(&den[g], __ATOMIC_RELAXED,
                                         __HIP_MEMORY_SCOPE_AGENT);
            float nm = __hip_atomic_load(&num[g], __ATOMIC_RELAXED,
                                         __HIP_MEMORY_SCOPE_AGENT);
            out[g] = (d > 0.0f) ? (SCALE_F * nm / d) : 0.0f;
        }
    }
}

extern "C" void kernel_launch(void* const* d_in, const int* in_sizes, int n_in,
                              void* d_out, int out_size, void* d_ws, size_t ws_size,
                              hipStream_t stream) {
    const float* x   = (const float*)d_in[0];
    const float* W1  = (const float*)d_in[1];
    const float* b1  = (const float*)d_in[2];
    const float* wr  = (const float*)d_in[3];
    const float* br  = (const float*)d_in[4];
    const float* wz  = (const float*)d_in[5];
    const float* bz  = (const float*)d_in[6];
    const int*   seg = (const int*)d_in[7];

    int N = in_sizes[7];     // 2097152
    int G = out_size;        // 8192

    float* num    = (float*)d_ws;
    float* den    = num + G;
    int*   ticket = (int*)(den + G);
    float* out    = (float*)d_out;

    int zn = 2 * G + 1;      // num, den, ticket
    zero_ws_kernel<<<(zn + 255) / 256, 256, 0, stream>>>(num, zn);

    long tokens_per_block = (long)BLOCK * TPT;   // 1024
    int  nblocks = (int)(((long)N + tokens_per_block - 1) / tokens_per_block);
    strength_main_kernel<<<nblocks, BLOCK, 0, stream>>>(
        x, W1, b1, wr, br, wz, bz, seg, N, G, nblocks, num, den, ticket, out);
}

// Round 7
// 30.475 us; speedup vs baseline: 6.7581x; 6.7581x over previous
//
#include <hip/hip_runtime.h>

#define SCALE_F 173.71779276130078f   // 400 / ln(10)
#define BLOCK 256
#define TPT 4                         // consecutive tokens per thread

__global__ void zero_ws_kernel(float* __restrict__ ws, int n) {
    int i = blockIdx.x * 256 + threadIdx.x;
    if (i < n) ws[i] = 0.0f;
}

__global__ __launch_bounds__(BLOCK, 8) void strength_main_kernel(
    const float* __restrict__ x,    // [N][6]
    const float* __restrict__ W1,   // [6][32]
    const float* __restrict__ b1,   // [32]
    const float* __restrict__ wr,   // [32]
    const float* __restrict__ brp,  // scalar
    const float* __restrict__ wz,   // [32]
    const float* __restrict__ bzp,  // scalar
    const int*   __restrict__ seg,  // [N] sorted
    int N,
    float* __restrict__ num,        // [G]
    float* __restrict__ den)        // [G]
{
    const int tid  = threadIdx.x;
    const int lane = tid & 63;

    const int t0   = blockIdx.x * (BLOCK * TPT) + tid * TPT;
    const int kmax = (t0 >= N) ? 0 : ((N - t0 < TPT) ? (N - t0) : TPT);

    // ---- load 4 consecutive tokens (6 float4 = 96B) + 4 seg ids ----
    float a[TPT * 6];
    int   sg[TPT];
    if (kmax == TPT) {
        const float4* xp = (const float4*)(x + (size_t)t0 * 6);
        #pragma unroll
        for (int i = 0; i < 6; ++i) {
            float4 v = xp[i];
            a[4 * i + 0] = v.x; a[4 * i + 1] = v.y;
            a[4 * i + 2] = v.z; a[4 * i + 3] = v.w;
        }
        int4 s0v = *(const int4*)(seg + t0);
        sg[0] = s0v.x; sg[1] = s0v.y; sg[2] = s0v.z; sg[3] = s0v.w;
    } else {
        #pragma unroll
        for (int k = 0; k < TPT; ++k) {
            if (k < kmax) {
                const float* xp = x + (size_t)(t0 + k) * 6;
                #pragma unroll
                for (int i = 0; i < 6; ++i) a[k * 6 + i] = xp[i];
                sg[k] = seg[t0 + k];
            } else {
                #pragma unroll
                for (int i = 0; i < 6; ++i) a[k * 6 + i] = 0.0f;
                sg[k] = -1;
            }
        }
    }

    const float brv = *brp;   // uniform -> s_load
    const float bzv = *bzp;

    float r[TPT], z[TPT];
    #pragma unroll
    for (int k = 0; k < TPT; ++k) { r[k] = brv; z[k] = bzv; }

    // ---- MLP over 16 column-pairs. Weights are wave-uniform global derefs
    //      -> s_load into SGPRs (constant cache); no LDS in the hot path. ----
    #pragma unroll 2
    for (int c = 0; c < 16; ++c) {
        const float2 w0 = *(const float2*)&W1[0 * 32 + 2 * c];
        const float2 w1 = *(const float2*)&W1[1 * 32 + 2 * c];
        const float2 w2 = *(const float2*)&W1[2 * 32 + 2 * c];
        const float2 w3 = *(const float2*)&W1[3 * 32 + 2 * c];
        const float2 w4 = *(const float2*)&W1[4 * 32 + 2 * c];
        const float2 w5 = *(const float2*)&W1[5 * 32 + 2 * c];
        const float2 bb = *(const float2*)&b1[2 * c];
        const float2 rr = *(const float2*)&wr[2 * c];
        const float2 zz = *(const float2*)&wz[2 * c];
        #pragma unroll
        for (int k = 0; k < TPT; ++k) {
            const float a0 = a[k*6+0], a1 = a[k*6+1], a2 = a[k*6+2];
            const float a3 = a[k*6+3], a4 = a[k*6+4], a5 = a[k*6+5];
            float h0 = fmaf(a0, w0.x, fmaf(a1, w1.x, fmaf(a2, w2.x,
                       fmaf(a3, w3.x, fmaf(a4, w4.x, fmaf(a5, w5.x, bb.x))))));
            float h1 = fmaf(a0, w0.y, fmaf(a1, w1.y, fmaf(a2, w2.y,
                       fmaf(a3, w3.y, fmaf(a4, w4.y, fmaf(a5, w5.y, bb.y))))));
            h0 = fmaxf(h0, 0.0f);
            h1 = fmaxf(h1, 0.0f);
            r[k] = fmaf(h0, rr.x, fmaf(h1, rr.y, r[k]));
            z[k] = fmaf(h0, zz.x, fmaf(h1, zz.y, z[k]));
        }
    }

    // ---- per-thread serial run accumulation; interior boundaries flush
    //      straight to global (adds commute -> correct) ----
    int   key = (kmax > 0) ? sg[0] : -1;
    float E = 0.0f, ER = 0.0f;
    #pragma unroll
    for (int k = 0; k < TPT; ++k) {
        if (k < kmax) {
            float e = __expf(z[k]);        // no max-shift: ratio invariant
            if (sg[k] != key) {            // rare (~1.5% of threads)
                atomicAdd(&den[key], E);
                atomicAdd(&num[key], ER);
                key = sg[k]; E = 0.0f; ER = 0.0f;
            }
            E += e; ER = fmaf(e, r[k], ER);
        }
    }

    // ---- one segmented inclusive scan per wave over lane tails ----
    #pragma unroll
    for (int d = 1; d < 64; d <<= 1) {
        int   k2 = __shfl_up(key, d);
        float E2 = __shfl_up(E,   d);
        float R2 = __shfl_up(ER,  d);
        if (lane >= d && k2 == key) { E += E2; ER += R2; }
    }
    int knext = __shfl_down(key, 1);
    bool last = (lane == 63) || (knext != key);
    if (last && key >= 0) {
        atomicAdd(&den[key], E);
        atomicAdd(&num[key], ER);
    }
}

__global__ void finalize_kernel(const float* __restrict__ num,
                                const float* __restrict__ den,
                                float* __restrict__ out, int G) {
    int g = blockIdx.x * 256 + threadIdx.x;
    if (g < G) {
        float d = den[g];
        out[g] = (d > 0.0f) ? (SCALE_F * num[g] / d) : 0.0f;
    }
}

extern "C" void kernel_launch(void* const* d_in, const int* in_sizes, int n_in,
                              void* d_out, int out_size, void* d_ws, size_t ws_size,
                              hipStream_t stream) {
    const float* x   = (const float*)d_in[0];
    const float* W1  = (const float*)d_in[1];
    const float* b1  = (const float*)d_in[2];
    const float* wr  = (const float*)d_in[3];
    const float* br  = (const float*)d_in[4];
    const float* wz  = (const float*)d_in[5];
    const float* bz  = (const float*)d_in[6];
    const int*   seg = (const int*)d_in[7];

    int N = in_sizes[7];     // 2097152
    int G = out_size;        // 8192

    float* num = (float*)d_ws;
    float* den = num + G;
    float* out = (float*)d_out;

    int zn = 2 * G;
    zero_ws_kernel<<<(zn + 255) / 256, 256, 0, stream>>>(num, zn);

    long tokens_per_block = (long)BLOCK * TPT;   // 1024
    int  nblocks = (int)(((long)N + tokens_per_block - 1) / tokens_per_block);
    strength_main_kernel<<<nblocks, BLOCK, 0, stream>>>(
        x, W1, b1, wr, br, wz, bz, seg, N, num, den);

    finalize_kernel<<<(G + 255) / 256, 256, 0, stream>>>(num, den, out, G);
}